// Round 12
// baseline (189.589 us; speedup 1.0000x reference)
//
#include <hip/hip_runtime.h>

#define BB 2
#define SEQ 2048
#define DIM 768
#define NH 12
#define HD 64

typedef _Float16 half8 __attribute__((ext_vector_type(8)));
typedef _Float16 half4 __attribute__((ext_vector_type(4)));
typedef float floatx4 __attribute__((ext_vector_type(4)));

// Async global->LDS DMA, 16 B per lane; LDS dest = wave-uniform base + lane*16.
__device__ __forceinline__ void gl_lds16(const _Float16* g, _Float16* l) {
    __builtin_amdgcn_global_load_lds(
        (const __attribute__((address_space(1))) void*)g,
        (__attribute__((address_space(3))) void*)l, 16, 0, 0);
}

// ---------------------------------------------------------------------------
// One-shot fp32 -> f16 convert for x, W_kqv, W_proj (block ranges).
// ---------------------------------------------------------------------------
__global__ __launch_bounds__(256)
void cvt3(const float* __restrict__ s0, _Float16* __restrict__ d0, int nb0,
          const float* __restrict__ s1, _Float16* __restrict__ d1, int nb1,
          const float* __restrict__ s2, _Float16* __restrict__ d2) {
    int b = blockIdx.x;
    const float* s; _Float16* d;
    if (b < nb0)            { s = s0; d = d0; }
    else if (b < nb0 + nb1) { s = s1; d = d1; b -= nb0; }
    else                    { s = s2; d = d2; b -= nb0 + nb1; }
    const int i = (b * 256 + threadIdx.x) * 8;
    float4 a = *(const float4*)(s + i);
    float4 c = *(const float4*)(s + i + 4);
    half8 h;
    h[0] = (_Float16)a.x; h[1] = (_Float16)a.y; h[2] = (_Float16)a.z; h[3] = (_Float16)a.w;
    h[4] = (_Float16)c.x; h[5] = (_Float16)c.y; h[6] = (_Float16)c.z; h[7] = (_Float16)c.w;
    *(half8*)(d + i) = h;
}

// ---------------------------------------------------------------------------
// Double-buffered m97-style GEMM core: BM=BN=128, BK=32, 4 waves (2x2).
// ---------------------------------------------------------------------------
#define GEMM_CORE(APTR, BPTR)                                                   \
    __shared__ _Float16 Asl[2][128 * 32];                                       \
    __shared__ _Float16 Bsl[2][128 * 32];                                       \
    const int t = threadIdx.x, w = t >> 6, lane = t & 63;                       \
    const int quad = lane >> 4, l15 = lane & 15;                                \
    const int wm = w >> 1, wn = w & 1;                                          \
    const int m0 = blockIdx.y * 128, c0 = blockIdx.x * 128;                     \
    const floatx4 z4 = {0.f, 0.f, 0.f, 0.f};                                    \
    floatx4 acc[4][4];                                                          \
    _Pragma("unroll") for (int i = 0; i < 4; ++i)                               \
        _Pragma("unroll") for (int j = 0; j < 4; ++j) acc[i][j] = z4;           \
    const _Float16* pA = APTR + (size_t)(m0 + w * 32 + l15) * DIM + quad * 8;   \
    const _Float16* pB = BPTR + (size_t)(c0 + w * 32 + l15) * DIM + quad * 8;   \
    gl_lds16(pA,            &Asl[0][(w * 2 + 0) * 512]);                        \
    gl_lds16(pA + 16 * DIM, &Asl[0][(w * 2 + 1) * 512]);                        \
    gl_lds16(pB,            &Bsl[0][(w * 2 + 0) * 512]);                        \
    gl_lds16(pB + 16 * DIM, &Bsl[0][(w * 2 + 1) * 512]);                        \
    for (int k0 = 0, it = 0; k0 < DIM; k0 += 32, ++it) {                        \
        const int buf = it & 1;                                                 \
        __syncthreads();                                                        \
        if (k0 + 32 < DIM) {                                                    \
            gl_lds16(pA + k0 + 32,            &Asl[buf ^ 1][(w * 2 + 0) * 512]);\
            gl_lds16(pA + k0 + 32 + 16 * DIM, &Asl[buf ^ 1][(w * 2 + 1) * 512]);\
            gl_lds16(pB + k0 + 32,            &Bsl[buf ^ 1][(w * 2 + 0) * 512]);\
            gl_lds16(pB + k0 + 32 + 16 * DIM, &Bsl[buf ^ 1][(w * 2 + 1) * 512]);\
        }                                                                       \
        half8 af[4], bf[4];                                                     \
        _Pragma("unroll") for (int i = 0; i < 4; ++i)                           \
            af[i] = *(const half8*)&Asl[buf][(wm * 4 + i) * 512 + lane * 8];    \
        _Pragma("unroll") for (int j = 0; j < 4; ++j)                           \
            bf[j] = *(const half8*)&Bsl[buf][(wn * 4 + j) * 512 + lane * 8];    \
        _Pragma("unroll") for (int i = 0; i < 4; ++i)                           \
            _Pragma("unroll") for (int j = 0; j < 4; ++j)                       \
                acc[i][j] = __builtin_amdgcn_mfma_f32_16x16x32_f16(             \
                    af[i], bf[j], acc[i][j], 0, 0, 0);                          \
    }

// KQV: N=2304 (18 blocks of 128), scatter epilogue into k/q/v f16 buffers.
__global__ __launch_bounds__(256)
void kqv_gemm2(const _Float16* __restrict__ xh, const _Float16* __restrict__ Wh,
               const float* __restrict__ bias, _Float16* __restrict__ kb,
               _Float16* __restrict__ qb, _Float16* __restrict__ vb) {
    GEMM_CORE(xh, Wh)
    #pragma unroll
    for (int j = 0; j < 4; ++j) {
        const int cbase = c0 + (wn * 4 + j) * 16;
        const int h = cbase / 192;
        const int rem = cbase - h * 192;
        const int part = rem >> 6;
        const int d = (rem & 63) + l15;
        _Float16* dst = (part == 0) ? kb : (part == 1 ? qb : vb);
        const float bv = bias[cbase + l15];
        #pragma unroll
        for (int i = 0; i < 4; ++i)
            #pragma unroll
            for (int r = 0; r < 4; ++r) {
                const int m = m0 + (wm * 4 + i) * 16 + quad * 4 + r;
                const int bidx = m >> 11, n = m & (SEQ - 1);
                dst[(((size_t)(bidx * NH + h) * SEQ + n) << 6) + d] =
                    (_Float16)(acc[i][j][r] + bv);
            }
    }
}

// ---------------------------------------------------------------------------
// Proj GEMM, BM=128 x BN=64 (grid 12 x 32 = 384 blocks for occupancy).
// ---------------------------------------------------------------------------
__global__ __launch_bounds__(256)
void proj_gemm3(const _Float16* __restrict__ A, const _Float16* __restrict__ Wh,
                const float* __restrict__ bias, float* __restrict__ out) {
    __shared__ _Float16 Asl[2][128 * 32];
    __shared__ _Float16 Bsl[2][64 * 32];
    const int t = threadIdx.x, w = t >> 6, lane = t & 63;
    const int quad = lane >> 4, l15 = lane & 15;
    const int wm = w >> 1, wn = w & 1;
    const int m0 = blockIdx.y * 128, c0 = blockIdx.x * 64;
    const floatx4 z4 = {0.f, 0.f, 0.f, 0.f};
    floatx4 acc[4][2];
    #pragma unroll
    for (int i = 0; i < 4; ++i)
        #pragma unroll
        for (int j = 0; j < 2; ++j) acc[i][j] = z4;
    const _Float16* pA = A  + (size_t)(m0 + w * 32 + l15) * DIM + quad * 8;
    const _Float16* pB = Wh + (size_t)(c0 + w * 16 + l15) * DIM + quad * 8;
    gl_lds16(pA,            &Asl[0][(w * 2 + 0) * 512]);
    gl_lds16(pA + 16 * DIM, &Asl[0][(w * 2 + 1) * 512]);
    gl_lds16(pB,            &Bsl[0][w * 512]);
    for (int k0 = 0, it = 0; k0 < DIM; k0 += 32, ++it) {
        const int buf = it & 1;
        __syncthreads();
        if (k0 + 32 < DIM) {
            gl_lds16(pA + k0 + 32,            &Asl[buf ^ 1][(w * 2 + 0) * 512]);
            gl_lds16(pA + k0 + 32 + 16 * DIM, &Asl[buf ^ 1][(w * 2 + 1) * 512]);
            gl_lds16(pB + k0 + 32,            &Bsl[buf ^ 1][w * 512]);
        }
        half8 af[4], bf[2];
        #pragma unroll
        for (int i = 0; i < 4; ++i)
            af[i] = *(const half8*)&Asl[buf][(wm * 4 + i) * 512 + lane * 8];
        #pragma unroll
        for (int j = 0; j < 2; ++j)
            bf[j] = *(const half8*)&Bsl[buf][(wn * 2 + j) * 512 + lane * 8];
        #pragma unroll
        for (int i = 0; i < 4; ++i)
            #pragma unroll
            for (int j = 0; j < 2; ++j)
                acc[i][j] = __builtin_amdgcn_mfma_f32_16x16x32_f16(
                    af[i], bf[j], acc[i][j], 0, 0, 0);
    }
    #pragma unroll
    for (int j = 0; j < 2; ++j) {
        const int cbase = c0 + (wn * 2 + j) * 16;
        const float bv = bias[cbase + l15];
        #pragma unroll
        for (int i = 0; i < 4; ++i)
            #pragma unroll
            for (int r = 0; r < 4; ++r) {
                const int m = m0 + (wm * 4 + i) * 16 + quad * 4 + r;
                out[(size_t)m * DIM + cbase + l15] = acc[i][j][r] + bv;
            }
    }
}

// ---------------------------------------------------------------------------
// V transpose: vb [B][H][SEQ][HD] -> vbT [B][H][HD][SEQ]  (f16)
// ---------------------------------------------------------------------------
__global__ __launch_bounds__(256)
void v_transpose(const _Float16* __restrict__ vb, _Float16* __restrict__ vbT) {
    __shared__ _Float16 T[64 * 72];
    const int t = threadIdx.x;
    const int s0 = blockIdx.x * 64;
    const size_t base = (size_t)blockIdx.y * (SEQ * HD);
    {
        const int s = t >> 2, doff = (t & 3) * 16;
        const _Float16* src = vb + base + (size_t)(s0 + s) * HD + doff;
        *(half8*)&T[s * 72 + doff]     = *(const half8*)src;
        *(half8*)&T[s * 72 + doff + 8] = *(const half8*)(src + 8);
    }
    __syncthreads();
    {
        const int d = t >> 2, soff = (t & 3) * 16;
        half8 o0, o1;
        #pragma unroll
        for (int k = 0; k < 8; ++k) o0[k] = T[(soff + k) * 72 + d];
        #pragma unroll
        for (int k = 0; k < 8; ++k) o1[k] = T[(soff + 8 + k) * 72 + d];
        _Float16* dst = vbT + base + (size_t)d * SEQ + s0 + soff;
        *(half8*)dst       = o0;
        *(half8*)(dst + 8) = o1;
    }
}

// ---------------------------------------------------------------------------
// Flash attention, MFMA, K-SPLIT, 32 Q-rows/wave.
//  * S computed TRANSPOSED (swap MFMA operands) -> lane holds 4 consecutive j
//    per Q-row -> P stored with packed cvt + ds_write_b64 (4/rt/tile).
//  * Row-sum l via ones-column MFMA (lands in O's C-layout rows; no shuffles).
//  * One shared P buffer for both rt tiles -> LDS 40960 B (4 blocks/CU).
// P LDS layout: row i (stride 64 halves), 4-half slots XOR-swizzled with
// ((i&7)<<1) (pair-preserving so b128 reads stay contiguous).
// ---------------------------------------------------------------------------
__global__ __launch_bounds__(256)
void attn_mfma(const _Float16* __restrict__ qb, const _Float16* __restrict__ kbuf,
               const _Float16* __restrict__ vbT, _Float16* __restrict__ sa,
               _Float16* __restrict__ Opart, float* __restrict__ lpart) {
    __shared__ _Float16 Kl[2][64 * 64];
    __shared__ _Float16 Vl[2][64 * 64];
    __shared__ _Float16 Pl[4][16 * 64];   // shared by both rt of wave w
    // decode (q, p, np) from u in [0,40), heavy partitions first
    int u = 39 - blockIdx.x, q, p, np;
    if (u < 4)       { q = u;               p = 0;     np = 1; }
    else if (u < 12) { int v = u - 4;  q = 4  + (v >> 1); p = v & 1; np = 2; }
    else if (u < 24) { int v = u - 12; q = 8  + v / 3;    p = v % 3; np = 3; }
    else             { int v = u - 24; q = 12 + (v >> 2); p = v & 3; np = 4; }
    const int ntiles = 2 * q + 2;
    const int kt0 = p * 8;
    const int ktn = (p == np - 1) ? (ntiles - kt0) : 8;

    const int bh = blockIdx.y;
    const int t = threadIdx.x, w = t >> 6, lane = t & 63, quad = lane >> 4, l15 = lane & 15;
    const size_t base = (size_t)bh * (SEQ * HD);
    const int i0 = q * 128 + w * 32;      // wave's first Q row
    _Float16* Pw = Pl[w];
    const _Float16* Kg = kbuf + base;
    const _Float16* Vg = vbT + base;

    const int lr = lane >> 3, gg = lane & 7;
    const int gs = (gg ^ (lr & 7)) * 8;

    half8 aq[2][2];
    const _Float16 qs = (_Float16)(0.125f * 1.44269504f);   // 1/sqrt(HD)*log2(e)
    #pragma unroll
    for (int rt = 0; rt < 2; ++rt)
        #pragma unroll
        for (int ks = 0; ks < 2; ++ks) {
            aq[rt][ks] = *(const half8*)(qb + base +
                          (size_t)(i0 + rt * 16 + l15) * HD + ks * 32 + quad * 8);
            #pragma unroll
            for (int k = 0; k < 8; ++k) aq[rt][ks][k] *= qs;
        }

    half8 ones;
    #pragma unroll
    for (int k = 0; k < 8; ++k) ones[k] = (_Float16)1.0f;

    const floatx4 z4 = {0.f, 0.f, 0.f, 0.f};
    floatx4 O[2][4], l_acc[2];
    #pragma unroll
    for (int rt = 0; rt < 2; ++rt) {
        l_acc[rt] = z4;
        #pragma unroll
        for (int k = 0; k < 4; ++k) O[rt][k] = z4;
    }

    // prologue: stage first tile into buffer 0
    #pragma unroll
    for (int pp = 0; pp < 2; ++pp) {
        const int c = w * 2 + pp, row = c * 8 + lr;
        gl_lds16(Kg + (size_t)(kt0 * 64 + row) * HD + gs,  &Kl[0][c * 512]);
        gl_lds16(Vg + (size_t)row * SEQ + kt0 * 64 + gs,   &Vl[0][c * 512]);
    }

    const int swz = l15 & 7;
    const int pmask = (l15 & 7) << 1;                 // P slot XOR (pair-safe)
    const int prbase = l15 * 64;                      // P row base (halves)

    for (int it = 0; it < ktn; ++it) {
        const int kt = kt0 + it;
        const int buf = it & 1;
        const int j0 = kt * 64;
        __syncthreads();   // staging of `buf` drained; prev compute on buf^1 done

        if (it + 1 < ktn) {
            const _Float16* Kn = Kg + (size_t)(j0 + 64) * HD;
            const _Float16* Vn = Vg + (j0 + 64);
            #pragma unroll
            for (int pp = 0; pp < 2; ++pp) {
                const int c = w * 2 + pp, row = c * 8 + lr;
                gl_lds16(Kn + (size_t)row * HD + gs,  &Kl[buf ^ 1][c * 512]);
                gl_lds16(Vn + (size_t)row * SEQ + gs, &Vl[buf ^ 1][c * 512]);
            }
        }
        if (j0 > i0 + 31) continue;   // fully masked for this wave

        // S^T = K . Q^T : lane holds (j = j0 + nt*16 + quad*4 + r, i = i0+rt*16+l15)
        floatx4 S[2][4];
        #pragma unroll
        for (int rt = 0; rt < 2; ++rt)
            #pragma unroll
            for (int nt = 0; nt < 4; ++nt) S[rt][nt] = z4;
        #pragma unroll
        for (int ks = 0; ks < 2; ++ks)
            #pragma unroll
            for (int nt = 0; nt < 4; ++nt) {
                half8 bk = *(const half8*)&Kl[buf][(nt * 16 + l15) * 64 +
                                                   (((ks * 4 + quad) ^ swz) << 3)];
                S[0][nt] = __builtin_amdgcn_mfma_f32_16x16x32_f16(bk, aq[0][ks], S[0][nt], 0, 0, 0);
                S[1][nt] = __builtin_amdgcn_mfma_f32_16x16x32_f16(bk, aq[1][ks], S[1][nt], 0, 0, 0);
            }

        // V fragments for both rt (registers survive the compiler fences)
        half8 bvr[2][4];
        #pragma unroll
        for (int ks = 0; ks < 2; ++ks)
            #pragma unroll
            for (int dt = 0; dt < 4; ++dt)
                bvr[ks][dt] = *(const half8*)&Vl[buf][(dt * 16 + l15) * 64 +
                                                      (((ks * 4 + quad) ^ swz) << 3)];

        const bool masked = (j0 + 63 > i0);
        #pragma unroll
        for (int rt = 0; rt < 2; ++rt) {
            asm volatile("" ::: "memory");   // WAR: prior P reads before new writes
            const int iq = i0 + rt * 16 + l15;
            #pragma unroll
            for (int nt = 0; nt < 4; ++nt) {
                float pv[4];
                if (masked) {
                    const int jb = j0 + nt * 16 + quad * 4;
                    #pragma unroll
                    for (int r = 0; r < 4; ++r) {
                        float e = exp2f(S[rt][nt][r]);
                        pv[r] = (jb + r > iq) ? 0.f : e;
                    }
                } else {
                    #pragma unroll
                    for (int r = 0; r < 4; ++r) pv[r] = exp2f(S[rt][nt][r]);
                }
                auto lo = __builtin_amdgcn_cvt_pkrtz(pv[0], pv[1]);
                auto hi = __builtin_amdgcn_cvt_pkrtz(pv[2], pv[3]);
                half4 pk;
                pk[0] = (_Float16)lo[0]; pk[1] = (_Float16)lo[1];
                pk[2] = (_Float16)hi[0]; pk[3] = (_Float16)hi[1];
                const int slot = (nt * 4 + quad) ^ pmask;
                *(half4*)&Pw[prbase + slot * 4] = pk;
            }
            asm volatile("" ::: "memory");   // RAW: P writes before fragment reads
            #pragma unroll
            for (int ks = 0; ks < 2; ++ks) {
                const int rslot = (ks * 8 + quad * 2) ^ pmask;
                half8 ap = *(const half8*)&Pw[prbase + rslot * 4];
                #pragma unroll
                for (int dt = 0; dt < 4; ++dt)
                    O[rt][dt] = __builtin_amdgcn_mfma_f32_16x16x32_f16(
                        ap, bvr[ks][dt], O[rt][dt], 0, 0, 0);
                l_acc[rt] = __builtin_amdgcn_mfma_f32_16x16x32_f16(
                    ap, ones, l_acc[rt], 0, 0, 0);
            }
        }
    }

    if (np == 1) {
        const int bidx = bh / NH, h = bh - bidx * NH;
        #pragma unroll
        for (int rt = 0; rt < 2; ++rt)
            #pragma unroll
            for (int r = 0; r < 4; ++r) {
                const float inv = 1.0f / l_acc[rt][r];
                const int i = i0 + rt * 16 + quad * 4 + r;
                #pragma unroll
                for (int dt = 0; dt < 4; ++dt)
                    sa[(size_t)(bidx * SEQ + i) * DIM + h * HD + dt * 16 + l15] =
                        (_Float16)(O[rt][dt][r] * inv);
            }
    } else {
        // partials: O (f16, 128x64) + l (fp32, 128) at slot (bh, q, p)
        const size_t slot = ((size_t)(bh * 16 + q) * 4 + p);
        _Float16* Od = Opart + slot * 8192;
        float*    ld = lpart + slot * 128;
        #pragma unroll
        for (int rt = 0; rt < 2; ++rt)
            #pragma unroll
            for (int r = 0; r < 4; ++r) {
                const int row = w * 32 + rt * 16 + quad * 4 + r;
                ld[row] = l_acc[rt][r];
                #pragma unroll
                for (int dt = 0; dt < 4; ++dt)
                    Od[row * 64 + dt * 16 + l15] = (_Float16)O[rt][dt][r];
            }
    }
}

// ---------------------------------------------------------------------------
// Combine K-split partials for q >= 4: sa = (sum_p O_p) / (sum_p l_p).
// ---------------------------------------------------------------------------
__global__ __launch_bounds__(256)
void attn_combine(const _Float16* __restrict__ Opart, const float* __restrict__ lpart,
                  _Float16* __restrict__ sa) {
    const int q = 4 + blockIdx.x;
    const int bh = blockIdx.y;
    const int np = (q < 8) ? 2 : (q < 12 ? 3 : 4);
    const int t = threadIdx.x;
    const int row = t >> 1, d0 = (t & 1) * 32;
    const size_t slot0 = (size_t)(bh * 16 + q) * 4;

    float lsum = 0.f;
    for (int p = 0; p < np; ++p) lsum += lpart[(slot0 + p) * 128 + row];

    float acc[32];
    #pragma unroll
    for (int k = 0; k < 32; ++k) acc[k] = 0.f;
    for (int p = 0; p < np; ++p) {
        const _Float16* src = Opart + (slot0 + p) * 8192 + row * 64 + d0;
        #pragma unroll
        for (int v = 0; v < 4; ++v) {
            half8 a = *(const half8*)(src + v * 8);
            #pragma unroll
            for (int k = 0; k < 8; ++k) acc[v * 8 + k] += (float)a[k];
        }
    }
    const float inv = 1.0f / lsum;
    const int bidx = bh / NH, h = bh - bidx * NH;
    _Float16* dst = sa + (size_t)(bidx * SEQ + q * 128 + row) * DIM + h * HD + d0;
    #pragma unroll
    for (int v = 0; v < 4; ++v) {
        half8 o;
        #pragma unroll
        for (int k = 0; k < 8; ++k) o[k] = (_Float16)(acc[v * 8 + k] * inv);
        *(half8*)(dst + v * 8) = o;
    }
}

// ---------------------------------------------------------------------------
extern "C" void kernel_launch(void* const* d_in, const int* in_sizes, int n_in,
                              void* d_out, int out_size, void* d_ws, size_t ws_size,
                              hipStream_t stream) {
    (void)in_sizes; (void)n_in; (void)out_size; (void)ws_size;
    const float* x  = (const float*)d_in[0];
    const float* Wk = (const float*)d_in[1];
    const float* bk = (const float*)d_in[2];
    const float* Wp = (const float*)d_in[3];
    const float* bp = (const float*)d_in[4];
    float* out = (float*)d_out;

    _Float16* ws = (_Float16*)d_ws;
    const size_t per = (size_t)BB * NH * SEQ * HD;          // 3,145,728 halves
    const int nx = BB * SEQ * DIM;                          // 3,145,728
    const int nwk = NH * 3 * HD * DIM;                      // 1,769,472
    const int nwp = DIM * DIM;                              //   589,824
    _Float16* kb  = ws;
    _Float16* qb  = ws + per;
    _Float16* vb  = ws + 2 * per;
    _Float16* vbT = ws + 3 * per;
    _Float16* sa  = ws + 4 * per;
    _Float16* xh  = ws + 5 * per;
    _Float16* Wkh = xh + nx;
    _Float16* Wph = Wkh + nwk;
    _Float16* Opart = Wph + nwp;                            // 24*16*4*8192 f16
    float*    lpart = (float*)(Opart + (size_t)24 * 16 * 4 * 8192);

    const int nb0 = nx / 2048, nb1 = nwk / 2048, nb2 = nwp / 2048;
    cvt3<<<dim3(nb0 + nb1 + nb2), 256, 0, stream>>>(x, xh, nb0, Wk, Wkh, nb1, Wp, Wph);

    kqv_gemm2  <<<dim3(18, 32), 256, 0, stream>>>(xh, Wkh, bk, kb, qb, vb);
    v_transpose<<<dim3(32, 24), 256, 0, stream>>>(vb, vbT);
    attn_mfma  <<<dim3(40, 24), 256, 0, stream>>>(qb, kb, vbT, sa, Opart, lpart);
    attn_combine<<<dim3(12, 24), 256, 0, stream>>>(Opart, lpart, sa);
    proj_gemm3 <<<dim3(12, 32), 256, 0, stream>>>(sa, Wph, bp, out);
}

// Round 13
// 187.545 us; speedup vs baseline: 1.0109x; 1.0109x over previous
//
#include <hip/hip_runtime.h>

#define BB 2
#define SEQ 2048
#define DIM 768
#define NH 12
#define HD 64

typedef _Float16 half8 __attribute__((ext_vector_type(8)));
typedef _Float16 half4 __attribute__((ext_vector_type(4)));
typedef float floatx4 __attribute__((ext_vector_type(4)));

// Async global->LDS DMA, 16 B per lane; LDS dest = wave-uniform base + lane*16.
__device__ __forceinline__ void gl_lds16(const _Float16* g, _Float16* l) {
    __builtin_amdgcn_global_load_lds(
        (const __attribute__((address_space(1))) void*)g,
        (__attribute__((address_space(3))) void*)l, 16, 0, 0);
}

// ---------------------------------------------------------------------------
// One-shot fp32 -> f16 convert for x, W_kqv, W_proj (block ranges).
// ---------------------------------------------------------------------------
__global__ __launch_bounds__(256)
void cvt3(const float* __restrict__ s0, _Float16* __restrict__ d0, int nb0,
          const float* __restrict__ s1, _Float16* __restrict__ d1, int nb1,
          const float* __restrict__ s2, _Float16* __restrict__ d2) {
    int b = blockIdx.x;
    const float* s; _Float16* d;
    if (b < nb0)            { s = s0; d = d0; }
    else if (b < nb0 + nb1) { s = s1; d = d1; b -= nb0; }
    else                    { s = s2; d = d2; b -= nb0 + nb1; }
    const int i = (b * 256 + threadIdx.x) * 8;
    float4 a = *(const float4*)(s + i);
    float4 c = *(const float4*)(s + i + 4);
    half8 h;
    h[0] = (_Float16)a.x; h[1] = (_Float16)a.y; h[2] = (_Float16)a.z; h[3] = (_Float16)a.w;
    h[4] = (_Float16)c.x; h[5] = (_Float16)c.y; h[6] = (_Float16)c.z; h[7] = (_Float16)c.w;
    *(half8*)(d + i) = h;
}

// ---------------------------------------------------------------------------
// Double-buffered m97-style GEMM core: BM=BN=128, BK=32, 4 waves (2x2).
// ---------------------------------------------------------------------------
#define GEMM_CORE(APTR, BPTR)                                                   \
    __shared__ _Float16 Asl[2][128 * 32];                                       \
    __shared__ _Float16 Bsl[2][128 * 32];                                       \
    const int t = threadIdx.x, w = t >> 6, lane = t & 63;                       \
    const int quad = lane >> 4, l15 = lane & 15;                                \
    const int wm = w >> 1, wn = w & 1;                                          \
    const int m0 = blockIdx.y * 128, c0 = blockIdx.x * 128;                     \
    const floatx4 z4 = {0.f, 0.f, 0.f, 0.f};                                    \
    floatx4 acc[4][4];                                                          \
    _Pragma("unroll") for (int i = 0; i < 4; ++i)                               \
        _Pragma("unroll") for (int j = 0; j < 4; ++j) acc[i][j] = z4;           \
    const _Float16* pA = APTR + (size_t)(m0 + w * 32 + l15) * DIM + quad * 8;   \
    const _Float16* pB = BPTR + (size_t)(c0 + w * 32 + l15) * DIM + quad * 8;   \
    gl_lds16(pA,            &Asl[0][(w * 2 + 0) * 512]);                        \
    gl_lds16(pA + 16 * DIM, &Asl[0][(w * 2 + 1) * 512]);                        \
    gl_lds16(pB,            &Bsl[0][(w * 2 + 0) * 512]);                        \
    gl_lds16(pB + 16 * DIM, &Bsl[0][(w * 2 + 1) * 512]);                        \
    for (int k0 = 0, it = 0; k0 < DIM; k0 += 32, ++it) {                        \
        const int buf = it & 1;                                                 \
        __syncthreads();                                                        \
        if (k0 + 32 < DIM) {                                                    \
            gl_lds16(pA + k0 + 32,            &Asl[buf ^ 1][(w * 2 + 0) * 512]);\
            gl_lds16(pA + k0 + 32 + 16 * DIM, &Asl[buf ^ 1][(w * 2 + 1) * 512]);\
            gl_lds16(pB + k0 + 32,            &Bsl[buf ^ 1][(w * 2 + 0) * 512]);\
            gl_lds16(pB + k0 + 32 + 16 * DIM, &Bsl[buf ^ 1][(w * 2 + 1) * 512]);\
        }                                                                       \
        half8 af[4], bf[4];                                                     \
        _Pragma("unroll") for (int i = 0; i < 4; ++i)                           \
            af[i] = *(const half8*)&Asl[buf][(wm * 4 + i) * 512 + lane * 8];    \
        _Pragma("unroll") for (int j = 0; j < 4; ++j)                           \
            bf[j] = *(const half8*)&Bsl[buf][(wn * 4 + j) * 512 + lane * 8];    \
        _Pragma("unroll") for (int i = 0; i < 4; ++i)                           \
            _Pragma("unroll") for (int j = 0; j < 4; ++j)                       \
                acc[i][j] = __builtin_amdgcn_mfma_f32_16x16x32_f16(             \
                    af[i], bf[j], acc[i][j], 0, 0, 0);                          \
    }

// KQV: N=2304 (18 blocks of 128).  K and Q scattered row-major [bh][n][d];
// V written DIRECTLY TRANSPOSED into vbT [bh][d][n] — the C-layout gives 4
// consecutive n at fixed d per lane = packed half4 (8 B) contiguous stores.
__global__ __launch_bounds__(256)
void kqv_gemm2(const _Float16* __restrict__ xh, const _Float16* __restrict__ Wh,
               const float* __restrict__ bias, _Float16* __restrict__ kb,
               _Float16* __restrict__ qb, _Float16* __restrict__ vbT) {
    GEMM_CORE(xh, Wh)
    #pragma unroll
    for (int j = 0; j < 4; ++j) {
        const int cbase = c0 + (wn * 4 + j) * 16;
        const int h = cbase / 192;
        const int rem = cbase - h * 192;
        const int part = rem >> 6;
        const int d = (rem & 63) + l15;
        const float bv = bias[cbase + l15];
        if (part == 2) {
            #pragma unroll
            for (int i = 0; i < 4; ++i) {
                const int m = m0 + (wm * 4 + i) * 16 + quad * 4;
                const int bidx = m >> 11, n = m & (SEQ - 1);
                half4 pk;
                #pragma unroll
                for (int r = 0; r < 4; ++r) pk[r] = (_Float16)(acc[i][j][r] + bv);
                *(half4*)(vbT + ((size_t)(bidx * NH + h) * HD + d) * SEQ + n) = pk;
            }
        } else {
            _Float16* dst = (part == 0) ? kb : qb;
            #pragma unroll
            for (int i = 0; i < 4; ++i)
                #pragma unroll
                for (int r = 0; r < 4; ++r) {
                    const int m = m0 + (wm * 4 + i) * 16 + quad * 4 + r;
                    const int bidx = m >> 11, n = m & (SEQ - 1);
                    dst[(((size_t)(bidx * NH + h) * SEQ + n) << 6) + d] =
                        (_Float16)(acc[i][j][r] + bv);
                }
        }
    }
}

// ---------------------------------------------------------------------------
// Proj GEMM, BM=128 x BN=64 (grid 12 x 32 = 384 blocks for occupancy).
// ---------------------------------------------------------------------------
__global__ __launch_bounds__(256)
void proj_gemm3(const _Float16* __restrict__ A, const _Float16* __restrict__ Wh,
                const float* __restrict__ bias, float* __restrict__ out) {
    __shared__ _Float16 Asl[2][128 * 32];
    __shared__ _Float16 Bsl[2][64 * 32];
    const int t = threadIdx.x, w = t >> 6, lane = t & 63;
    const int quad = lane >> 4, l15 = lane & 15;
    const int wm = w >> 1, wn = w & 1;
    const int m0 = blockIdx.y * 128, c0 = blockIdx.x * 64;
    const floatx4 z4 = {0.f, 0.f, 0.f, 0.f};
    floatx4 acc[4][2];
    #pragma unroll
    for (int i = 0; i < 4; ++i)
        #pragma unroll
        for (int j = 0; j < 2; ++j) acc[i][j] = z4;
    const _Float16* pA = A  + (size_t)(m0 + w * 32 + l15) * DIM + quad * 8;
    const _Float16* pB = Wh + (size_t)(c0 + w * 16 + l15) * DIM + quad * 8;
    gl_lds16(pA,            &Asl[0][(w * 2 + 0) * 512]);
    gl_lds16(pA + 16 * DIM, &Asl[0][(w * 2 + 1) * 512]);
    gl_lds16(pB,            &Bsl[0][w * 512]);
    for (int k0 = 0, it = 0; k0 < DIM; k0 += 32, ++it) {
        const int buf = it & 1;
        __syncthreads();
        if (k0 + 32 < DIM) {
            gl_lds16(pA + k0 + 32,            &Asl[buf ^ 1][(w * 2 + 0) * 512]);
            gl_lds16(pA + k0 + 32 + 16 * DIM, &Asl[buf ^ 1][(w * 2 + 1) * 512]);
            gl_lds16(pB + k0 + 32,            &Bsl[buf ^ 1][w * 512]);
        }
        half8 af[4], bf[2];
        #pragma unroll
        for (int i = 0; i < 4; ++i)
            af[i] = *(const half8*)&Asl[buf][(wm * 4 + i) * 512 + lane * 8];
        #pragma unroll
        for (int j = 0; j < 2; ++j)
            bf[j] = *(const half8*)&Bsl[buf][(wn * 2 + j) * 512 + lane * 8];
        #pragma unroll
        for (int i = 0; i < 4; ++i)
            #pragma unroll
            for (int j = 0; j < 2; ++j)
                acc[i][j] = __builtin_amdgcn_mfma_f32_16x16x32_f16(
                    af[i], bf[j], acc[i][j], 0, 0, 0);
    }
    #pragma unroll
    for (int j = 0; j < 2; ++j) {
        const int cbase = c0 + (wn * 2 + j) * 16;
        const float bv = bias[cbase + l15];
        #pragma unroll
        for (int i = 0; i < 4; ++i)
            #pragma unroll
            for (int r = 0; r < 4; ++r) {
                const int m = m0 + (wm * 4 + i) * 16 + quad * 4 + r;
                out[(size_t)m * DIM + cbase + l15] = acc[i][j][r] + bv;
            }
    }
}

// ---------------------------------------------------------------------------
// Flash attention, MFMA, DEEP K-SPLIT (chunks of 4 tiles -> 1728 blocks,
// 6.75 blocks/CU work vs 4 resident -> stall overlap via block queue).
// 32 Q-rows/wave; transposed-S MFMA; packed P stores; l via ones-MFMA;
// shared P buffer (LDS 40960 B).  np(q) = (q+2)>>1, up to 8 partials.
// ---------------------------------------------------------------------------
__global__ __launch_bounds__(256)
void attn_mfma(const _Float16* __restrict__ qb, const _Float16* __restrict__ kbuf,
               const _Float16* __restrict__ vbT, _Float16* __restrict__ sa,
               _Float16* __restrict__ Opart, float* __restrict__ lpart) {
    __shared__ _Float16 Kl[2][64 * 64];
    __shared__ _Float16 Vl[2][64 * 64];
    __shared__ _Float16 Pl[4][16 * 64];   // shared by both rt of wave w
    // decode (q, p) from u in [0,72): q-pair k occupies [k(k+1), k(k+1)+2(k+1))
    int u = 71 - blockIdx.x;              // heavy partitions first
    int k = 0;
    while ((k + 1) * (k + 2) <= u) ++k;
    const int rem = u - k * (k + 1);
    const int hi = (rem >= (k + 1));
    const int q = 2 * k + hi;
    const int p = rem - (hi ? (k + 1) : 0);
    const int ntiles = 2 * q + 2;
    const int kt0 = p * 4;
    const int ktn = (ntiles - kt0 < 4) ? (ntiles - kt0) : 4;
    const int np = (q + 2) >> 1;

    const int bh = blockIdx.y;
    const int t = threadIdx.x, w = t >> 6, lane = t & 63, quad = lane >> 4, l15 = lane & 15;
    const size_t base = (size_t)bh * (SEQ * HD);
    const int i0 = q * 128 + w * 32;      // wave's first Q row
    _Float16* Pw = Pl[w];
    const _Float16* Kg = kbuf + base;
    const _Float16* Vg = vbT + base;

    const int lr = lane >> 3, gg = lane & 7;
    const int gs = (gg ^ (lr & 7)) * 8;

    half8 aq[2][2];
    const _Float16 qs = (_Float16)(0.125f * 1.44269504f);   // 1/sqrt(HD)*log2(e)
    #pragma unroll
    for (int rt = 0; rt < 2; ++rt)
        #pragma unroll
        for (int ks = 0; ks < 2; ++ks) {
            aq[rt][ks] = *(const half8*)(qb + base +
                          (size_t)(i0 + rt * 16 + l15) * HD + ks * 32 + quad * 8);
            #pragma unroll
            for (int kk = 0; kk < 8; ++kk) aq[rt][ks][kk] *= qs;
        }

    half8 ones;
    #pragma unroll
    for (int kk = 0; kk < 8; ++kk) ones[kk] = (_Float16)1.0f;

    const floatx4 z4 = {0.f, 0.f, 0.f, 0.f};
    floatx4 O[2][4], l_acc[2];
    #pragma unroll
    for (int rt = 0; rt < 2; ++rt) {
        l_acc[rt] = z4;
        #pragma unroll
        for (int kk = 0; kk < 4; ++kk) O[rt][kk] = z4;
    }

    // prologue: stage first tile into buffer 0
    #pragma unroll
    for (int pp = 0; pp < 2; ++pp) {
        const int c = w * 2 + pp, row = c * 8 + lr;
        gl_lds16(Kg + (size_t)(kt0 * 64 + row) * HD + gs,  &Kl[0][c * 512]);
        gl_lds16(Vg + (size_t)row * SEQ + kt0 * 64 + gs,   &Vl[0][c * 512]);
    }

    const int swz = l15 & 7;
    const int pmask = (l15 & 7) << 1;                 // P slot XOR (pair-safe)
    const int prbase = l15 * 64;                      // P row base (halves)

    for (int it = 0; it < ktn; ++it) {
        const int kt = kt0 + it;
        const int buf = it & 1;
        const int j0 = kt * 64;
        __syncthreads();   // staging of `buf` drained; prev compute on buf^1 done

        if (it + 1 < ktn) {
            const _Float16* Kn = Kg + (size_t)(j0 + 64) * HD;
            const _Float16* Vn = Vg + (j0 + 64);
            #pragma unroll
            for (int pp = 0; pp < 2; ++pp) {
                const int c = w * 2 + pp, row = c * 8 + lr;
                gl_lds16(Kn + (size_t)row * HD + gs,  &Kl[buf ^ 1][c * 512]);
                gl_lds16(Vn + (size_t)row * SEQ + gs, &Vl[buf ^ 1][c * 512]);
            }
        }
        if (j0 > i0 + 31) continue;   // fully masked for this wave

        // S^T = K . Q^T : lane holds (j = j0 + nt*16 + quad*4 + r, i = i0+rt*16+l15)
        floatx4 S[2][4];
        #pragma unroll
        for (int rt = 0; rt < 2; ++rt)
            #pragma unroll
            for (int nt = 0; nt < 4; ++nt) S[rt][nt] = z4;
        #pragma unroll
        for (int ks = 0; ks < 2; ++ks)
            #pragma unroll
            for (int nt = 0; nt < 4; ++nt) {
                half8 bk = *(const half8*)&Kl[buf][(nt * 16 + l15) * 64 +
                                                   (((ks * 4 + quad) ^ swz) << 3)];
                S[0][nt] = __builtin_amdgcn_mfma_f32_16x16x32_f16(bk, aq[0][ks], S[0][nt], 0, 0, 0);
                S[1][nt] = __builtin_amdgcn_mfma_f32_16x16x32_f16(bk, aq[1][ks], S[1][nt], 0, 0, 0);
            }

        // V fragments for both rt (registers survive the compiler fences)
        half8 bvr[2][4];
        #pragma unroll
        for (int ks = 0; ks < 2; ++ks)
            #pragma unroll
            for (int dt = 0; dt < 4; ++dt)
                bvr[ks][dt] = *(const half8*)&Vl[buf][(dt * 16 + l15) * 64 +
                                                      (((ks * 4 + quad) ^ swz) << 3)];

        const bool masked = (j0 + 63 > i0);
        #pragma unroll
        for (int rt = 0; rt < 2; ++rt) {
            asm volatile("" ::: "memory");   // WAR: prior P reads before new writes
            const int iq = i0 + rt * 16 + l15;
            #pragma unroll
            for (int nt = 0; nt < 4; ++nt) {
                float pv[4];
                if (masked) {
                    const int jb = j0 + nt * 16 + quad * 4;
                    #pragma unroll
                    for (int r = 0; r < 4; ++r) {
                        float e = exp2f(S[rt][nt][r]);
                        pv[r] = (jb + r > iq) ? 0.f : e;
                    }
                } else {
                    #pragma unroll
                    for (int r = 0; r < 4; ++r) pv[r] = exp2f(S[rt][nt][r]);
                }
                auto lo = __builtin_amdgcn_cvt_pkrtz(pv[0], pv[1]);
                auto hi2 = __builtin_amdgcn_cvt_pkrtz(pv[2], pv[3]);
                half4 pk;
                pk[0] = (_Float16)lo[0]; pk[1] = (_Float16)lo[1];
                pk[2] = (_Float16)hi2[0]; pk[3] = (_Float16)hi2[1];
                const int slot = (nt * 4 + quad) ^ pmask;
                *(half4*)&Pw[prbase + slot * 4] = pk;
            }
            asm volatile("" ::: "memory");   // RAW: P writes before fragment reads
            #pragma unroll
            for (int ks = 0; ks < 2; ++ks) {
                const int rslot = (ks * 8 + quad * 2) ^ pmask;
                half8 ap = *(const half8*)&Pw[prbase + rslot * 4];
                #pragma unroll
                for (int dt = 0; dt < 4; ++dt)
                    O[rt][dt] = __builtin_amdgcn_mfma_f32_16x16x32_f16(
                        ap, bvr[ks][dt], O[rt][dt], 0, 0, 0);
                l_acc[rt] = __builtin_amdgcn_mfma_f32_16x16x32_f16(
                    ap, ones, l_acc[rt], 0, 0, 0);
            }
        }
    }

    if (np == 1) {
        const int bidx = bh / NH, h = bh - bidx * NH;
        #pragma unroll
        for (int rt = 0; rt < 2; ++rt)
            #pragma unroll
            for (int r = 0; r < 4; ++r) {
                const float inv = 1.0f / l_acc[rt][r];
                const int i = i0 + rt * 16 + quad * 4 + r;
                #pragma unroll
                for (int dt = 0; dt < 4; ++dt)
                    sa[(size_t)(bidx * SEQ + i) * DIM + h * HD + dt * 16 + l15] =
                        (_Float16)(O[rt][dt][r] * inv);
            }
    } else {
        // partials: O (f16, 128x64) + l (fp32, 128) at slot (bh, q, p), p<8
        const size_t slot = ((size_t)(bh * 16 + q) * 8 + p);
        _Float16* Od = Opart + slot * 8192;
        float*    ld = lpart + slot * 128;
        #pragma unroll
        for (int rt = 0; rt < 2; ++rt)
            #pragma unroll
            for (int r = 0; r < 4; ++r) {
                const int row = w * 32 + rt * 16 + quad * 4 + r;
                ld[row] = l_acc[rt][r];
                #pragma unroll
                for (int dt = 0; dt < 4; ++dt)
                    Od[row * 64 + dt * 16 + l15] = (_Float16)O[rt][dt][r];
            }
    }
}

// ---------------------------------------------------------------------------
// Combine K-split partials for q >= 2: sa = (sum_p O_p) / (sum_p l_p).
// ---------------------------------------------------------------------------
__global__ __launch_bounds__(256)
void attn_combine(const _Float16* __restrict__ Opart, const float* __restrict__ lpart,
                  _Float16* __restrict__ sa) {
    const int q = 2 + blockIdx.x;         // 2..15
    const int bh = blockIdx.y;
    const int np = (q + 2) >> 1;
    const int t = threadIdx.x;
    const int row = t >> 1, d0 = (t & 1) * 32;
    const size_t slot0 = (size_t)(bh * 16 + q) * 8;

    float lsum = 0.f;
    for (int p = 0; p < np; ++p) lsum += lpart[(slot0 + p) * 128 + row];

    float acc[32];
    #pragma unroll
    for (int k = 0; k < 32; ++k) acc[k] = 0.f;
    for (int p = 0; p < np; ++p) {
        const _Float16* src = Opart + (slot0 + p) * 8192 + row * 64 + d0;
        #pragma unroll
        for (int v = 0; v < 4; ++v) {
            half8 a = *(const half8*)(src + v * 8);
            #pragma unroll
            for (int k = 0; k < 8; ++k) acc[v * 8 + k] += (float)a[k];
        }
    }
    const float inv = 1.0f / lsum;
    const int bidx = bh / NH, h = bh - bidx * NH;
    _Float16* dst = sa + (size_t)(bidx * SEQ + q * 128 + row) * DIM + h * HD + d0;
    #pragma unroll
    for (int v = 0; v < 4; ++v) {
        half8 o;
        #pragma unroll
        for (int k = 0; k < 8; ++k) o[k] = (_Float16)(acc[v * 8 + k] * inv);
        *(half8*)(dst + v * 8) = o;
    }
}

// ---------------------------------------------------------------------------
extern "C" void kernel_launch(void* const* d_in, const int* in_sizes, int n_in,
                              void* d_out, int out_size, void* d_ws, size_t ws_size,
                              hipStream_t stream) {
    (void)in_sizes; (void)n_in; (void)out_size; (void)ws_size;
    const float* x  = (const float*)d_in[0];
    const float* Wk = (const float*)d_in[1];
    const float* bk = (const float*)d_in[2];
    const float* Wp = (const float*)d_in[3];
    const float* bp = (const float*)d_in[4];
    float* out = (float*)d_out;

    _Float16* ws = (_Float16*)d_ws;
    const size_t per = (size_t)BB * NH * SEQ * HD;          // 3,145,728 halves
    const int nx = BB * SEQ * DIM;                          // 3,145,728
    const int nwk = NH * 3 * HD * DIM;                      // 1,769,472
    const int nwp = DIM * DIM;                              //   589,824
    _Float16* kb  = ws;
    _Float16* qb  = ws + per;
    _Float16* vbT = ws + 2 * per;
    _Float16* sa  = ws + 3 * per;
    _Float16* xh  = ws + 4 * per;
    _Float16* Wkh = xh + nx;
    _Float16* Wph = Wkh + nwk;
    _Float16* Opart = Wph + nwp;                            // 24*16*8*8192 f16
    float*    lpart = (float*)(Opart + (size_t)24 * 16 * 8 * 8192);

    const int nb0 = nx / 2048, nb1 = nwk / 2048, nb2 = nwp / 2048;
    cvt3<<<dim3(nb0 + nb1 + nb2), 256, 0, stream>>>(x, xh, nb0, Wk, Wkh, nb1, Wp, Wph);

    kqv_gemm2  <<<dim3(18, 32), 256, 0, stream>>>(xh, Wkh, bk, kb, qb, vbT);
    attn_mfma  <<<dim3(72, 24), 256, 0, stream>>>(qb, kb, vbT, sa, Opart, lpart);
    attn_combine<<<dim3(14, 24), 256, 0, stream>>>(Opart, lpart, sa);
    proj_gemm3 <<<dim3(12, 32), 256, 0, stream>>>(sa, Wph, bp, out);
}